// Round 6
// baseline (125.812 us; speedup 1.0000x reference)
//
#include <hip/hip_runtime.h>

#define BATCH 131072

typedef float v2f __attribute__((ext_vector_type(2)));

// ws layout (floats):
//  [0..53]     A: 6 matrices 3x3 (decoder collapsed: recon_k = (l^T A_k l)/(l^T l))
//  [64..99]    enc RX coeffs: gate g=bb*6+w -> ws[64+2g]=cos(tx/2), ws[65+2g]=sin(tx/2)
//  [128..511]  enc diag per block bb: ws[128+128*bb+2r]=Re D_r, +1=Im D_r

__device__ __forceinline__ float fast_tanh(float v) {
    float e = __expf(2.0f * v);
    return 1.0f - 2.0f / (e + 1.0f);
}

__device__ __forceinline__ v2f swap2(v2f v) { return __builtin_shufflevector(v, v, 1, 0); }

// ---------------------------------------------------------------------------
// prep (unchanged)
// ---------------------------------------------------------------------------
__global__ __launch_bounds__(256) void prep_kernel(const float* __restrict__ enc_w,
                                                   const float* __restrict__ dec_w,
                                                   float* __restrict__ ws) {
    __shared__ float gt[18][8];
    __shared__ float Sr[64][8];
    __shared__ float Si[64][8];
    const int t = threadIdx.x;

    if (t < 18) {
        float tx = dec_w[t * 3 + 0];
        float tz = dec_w[t * 3 + 1];
        float c = cosf(0.5f * tx), s = sinf(0.5f * tx);
        float ch = cosf(0.5f * tz), sh = sinf(0.5f * tz);
        gt[t][0] = c * ch;  gt[t][1] = -c * sh;
        gt[t][2] = -s * sh; gt[t][3] = -s * ch;
        gt[t][4] = s * sh;  gt[t][5] = -s * ch;
        gt[t][6] = c * ch;  gt[t][7] = c * sh;
    }

    const int cl = t & 7;
    const int pr = t >> 3;
    float* fSr = &Sr[0][0];
    float* fSi = &Si[0][0];
    for (int f = t; f < 512; f += 256) {
        int r = f >> 3, c = f & 7;
        fSr[f] = (r == c && c < 3) ? 1.0f : 0.0f;
        fSi[f] = 0.0f;
    }

    for (int bb = 0; bb < 3; ++bb) {
        for (int w = 0; w < 6; ++w) {
            __syncthreads();
            int g = bb * 6 + w;
            int p = 5 - w;
            float u00r = gt[g][0], u00i = gt[g][1], u01r = gt[g][2], u01i = gt[g][3];
            float u10r = gt[g][4], u10i = gt[g][5], u11r = gt[g][6], u11i = gt[g][7];
            int r0 = ((pr >> p) << (p + 1)) | (pr & ((1 << p) - 1));
            int r1 = r0 | (1 << p);
            float ar = Sr[r0][cl], ai = Si[r0][cl];
            float br = Sr[r1][cl], bi = Si[r1][cl];
            Sr[r0][cl] = u00r * ar - u00i * ai + u01r * br - u01i * bi;
            Si[r0][cl] = u00r * ai + u00i * ar + u01r * bi + u01i * br;
            Sr[r1][cl] = u10r * ar - u10i * ai + u11r * br - u11i * bi;
            Si[r1][cl] = u10r * ai + u10i * ar + u11r * bi + u11i * br;
        }
        __syncthreads();
        for (int f = t; f < 512; f += 256) {
            int r = f >> 3;
            if (__popc(r & (r >> 1)) & 1) {
                fSr[f] = -fSr[f];
                fSi[f] = -fSi[f];
            }
        }
    }
    __syncthreads();

    if (t < 54) {
        int k = t / 9, d = (t % 9) / 3, e = t % 3;
        float acc = 0.0f;
        for (int r = 0; r < 64; ++r) {
            float term = Sr[r][d] * Sr[r][e] + Si[r][d] * Si[r][e];
            acc += ((r >> (5 - k)) & 1) ? -term : term;
        }
        ws[t] = acc;
    }

    if (t < 18) {
        float tx = enc_w[t * 3 + 0];
        ws[64 + 2 * t] = cosf(0.5f * tx);
        ws[65 + 2 * t] = sinf(0.5f * tx);
    }

    if (t >= 64 && t < 256) {
        int idx = t - 64;
        int bb = idx >> 6, r = idx & 63;
        float phi = 0.0f;
        for (int k = 0; k < 6; ++k) {
            float tz = enc_w[(bb * 6 + k) * 3 + 1];
            phi += ((r >> (5 - k)) & 1) ? 0.5f * tz : -0.5f * tz;
        }
        float sgn = (__popc(r & (r >> 1)) & 1) ? -1.0f : 1.0f;
        ws[128 + bb * 128 + 2 * r] = sgn * cosf(phi);
        ws[129 + bb * 128 + 2 * r] = sgn * sinf(phi);
    }
}

// ---------------------------------------------------------------------------
// Pack-pair RX butterfly. State: 32 v2f packs; pack p = amps (2p, 2p+1);
// amp bit mapping: r = 2p + half. Wire w<5 acts on p bit (4-w) => MASK 16>>w.
// ---------------------------------------------------------------------------
template <int MASK>
__device__ __forceinline__ void rx_pk(v2f* zr, v2f* zi, float c, float s) {
#pragma unroll
    for (int p = 0; p < 32; ++p) {
        if (p & MASK) continue;
        int p1 = p | MASK;
        v2f ar = zr[p], ai = zi[p], br = zr[p1], bi = zi[p1];
        zr[p]  = c * ar + s * bi;
        zi[p]  = c * ai - s * br;
        zr[p1] = c * br + s * ai;
        zi[p1] = c * bi - s * ar;
    }
}

// ---------------------------------------------------------------------------
// main: ONE thread per batch element; full 64-amp state in 32+32 v2f packs.
// No cross-lane ops in the circuit. Block covers 256 elements.
// sWI layout: pack p -> [p*16 + 2d + half] = W[2p+half][d]; +12/+13 biases.
// ---------------------------------------------------------------------------
__global__ __launch_bounds__(256, 2) void qae_main(const float* __restrict__ x,
                                                   const float* __restrict__ Wp,
                                                   const float* __restrict__ bp,
                                                   const float* __restrict__ ws,
                                                   float* __restrict__ out) {
    __shared__ float sWI[512];
    __shared__ float sD[384];
    __shared__ float sRec[256 * 9];  // stride 9: conflict-free
    __shared__ float sLat[768];

    const int t = threadIdx.x;

    for (int f = t; f < 512; f += 256) {
        int p = f >> 4, e = f & 15;
        float val = 0.0f;
        if (e < 12)      val = Wp[(2 * p + (e & 1)) * 6 + (e >> 1)];
        else if (e < 14) val = bp[2 * p + (e - 12)];
        sWI[f] = val;
    }
    for (int f = t; f < 384; f += 256) sD[f] = ws[128 + f];
    __syncthreads();

    const size_t b = (size_t)blockIdx.x * 256 + t;
    const float* xp = x + b * 6;
    float2 x01 = *(const float2*)(xp);
    float2 x23 = *(const float2*)(xp + 2);
    float2 x45 = *(const float2*)(xp + 4);
    float xv[6] = {x01.x, x01.y, x23.x, x23.y, x45.x, x45.y};

    // h = tanh(xW^T+b): pack p = rows (2p, 2p+1); all LDS reads wave-uniform
    v2f zr[32], zi[32];
    v2f S2 = {0.0f, 0.0f};
#pragma unroll
    for (int p = 0; p < 32; ++p) {
        const float* wb = &sWI[p * 16];
        float4 c0 = *(const float4*)wb;
        float4 c1 = *(const float4*)(wb + 4);
        float4 c2 = *(const float4*)(wb + 8);
        float4 c3 = *(const float4*)(wb + 12);
        v2f a = {c3.x, c3.y};
        a += xv[0] * (v2f){c0.x, c0.y};
        a += xv[1] * (v2f){c0.z, c0.w};
        a += xv[2] * (v2f){c1.x, c1.y};
        a += xv[3] * (v2f){c1.z, c1.w};
        a += xv[4] * (v2f){c2.x, c2.y};
        a += xv[5] * (v2f){c2.z, c2.w};
        v2f th = {fast_tanh(a.x), fast_tanh(a.y)};
        zr[p] = th;
        zi[p] = (v2f){0.0f, 0.0f};
        S2 += th * th;
    }
    float invS = __builtin_amdgcn_rcpf(S2.x + S2.y);

    // encoder circuit, all register-local (last block's diagonal dropped: |D|=1)
#pragma unroll 1
    for (int bb = 0; bb < 3; ++bb) {
        const float* rx = ws + 64 + 12 * bb;   // uniform -> s_load
        rx_pk<16>(zr, zi, rx[0], rx[1]);       // wire 0: p bit4
        rx_pk<8>(zr, zi, rx[2], rx[3]);        // wire 1: p bit3
        rx_pk<4>(zr, zi, rx[4], rx[5]);        // wire 2: p bit2
        rx_pk<2>(zr, zi, rx[6], rx[7]);        // wire 3: p bit1
        rx_pk<1>(zr, zi, rx[8], rx[9]);        // wire 4: p bit0
        {                                       // wire 5: in-pack
            float c = rx[10], s = rx[11];
#pragma unroll
            for (int p = 0; p < 32; ++p) {
                v2f orr = zr[p], oi = zi[p];
                zr[p] = c * orr + s * swap2(oi);
                zi[p] = c * oi - s * swap2(orr);
            }
        }
        if (bb < 2) {
#pragma unroll
            for (int p = 0; p < 32; ++p) {
                float4 d = *(const float4*)&sD[bb * 128 + 4 * p];  // uniform broadcast
                v2f dr = {d.x, d.z}, di = {d.y, d.w};
                v2f orr = zr[p], oi = zi[p];
                zr[p] = dr * orr - di * oi;
                zi[p] = dr * oi + di * orr;
            }
        }
    }

    // latent: signs from r bits 5,4,3 = p bits 4,3,2; thread-local reduction
    v2f L0 = {0, 0}, L1 = {0, 0}, L2 = {0, 0};
#pragma unroll
    for (int p = 0; p < 32; ++p) {
        v2f pr = zr[p] * zr[p] + zi[p] * zi[p];
        L0 += (p & 16) ? -pr : pr;
        L1 += (p & 8) ? -pr : pr;
        L2 += (p & 4) ? -pr : pr;
    }
    float l0 = (L0.x + L0.y) * invS;
    float l1 = (L1.x + L1.y) * invS;
    float l2 = (L2.x + L2.y) * invS;

    // decoder collapsed: recon_k = (l^T A_k l)/(l^T l)  (A uniform -> s_load)
    float r2 = l0 * l0 + l1 * l1 + l2 * l2;
    float invr2 = __builtin_amdgcn_rcpf(r2);
    float lv[3] = {l0, l1, l2};
    float rec[6];
#pragma unroll
    for (int k = 0; k < 6; ++k) {
        float acc = 0.0f;
#pragma unroll
        for (int d = 0; d < 3; ++d)
#pragma unroll
            for (int e2 = 0; e2 < 3; ++e2) acc += ws[k * 9 + d * 3 + e2] * lv[d] * lv[e2];
        rec[k] = acc * invr2;
    }

    // stage latent + rec for coalesced output
    sLat[3 * t + 0] = l0;
    sLat[3 * t + 1] = l1;
    sLat[3 * t + 2] = l2;
#pragma unroll
    for (int d = 0; d < 6; ++d) sRec[t * 9 + d] = rec[d];
    __syncthreads();

    // latent out: fully coalesced (256 elements x 3)
#pragma unroll
    for (int f = 0; f < 3; ++f)
        out[(size_t)BATCH * 64 + (size_t)blockIdx.x * 768 + f * 256 + t] = sLat[f * 256 + t];

    // reconstructed = tanh(rec W^T + b): 4 lanes/element, packed rows
    const int bl = t >> 2, sub = t & 3;
#pragma unroll
    for (int q = 0; q < 4; ++q) {
        int el = 64 * q + bl;
        const float* rp = &sRec[el * 9];   // 4 sub-lanes broadcast; bl stride-9 conflict-free
        float rc0 = rp[0], rc1 = rp[1], rc2 = rp[2], rc3 = rp[3], rc4 = rp[4], rc5 = rp[5];
        const size_t ob = ((size_t)blockIdx.x * 256 + el) * 64;
#pragma unroll
        for (int k = 0; k < 8; ++k) {
            int p = sub + 4 * k;           // lanes 2-way on banks (free)
            const float* wb = &sWI[p * 16];
            float4 c0 = *(const float4*)wb;
            float4 c1 = *(const float4*)(wb + 4);
            float4 c2 = *(const float4*)(wb + 8);
            float4 c3 = *(const float4*)(wb + 12);
            v2f a = {c3.x, c3.y};
            a += rc0 * (v2f){c0.x, c0.y};
            a += rc1 * (v2f){c0.z, c0.w};
            a += rc2 * (v2f){c1.x, c1.y};
            a += rc3 * (v2f){c1.z, c1.w};
            a += rc4 * (v2f){c2.x, c2.y};
            a += rc5 * (v2f){c2.z, c2.w};
            float2 o = {fast_tanh(a.x), fast_tanh(a.y)};
            *(float2*)&out[ob + 2 * p] = o;
        }
    }
}

extern "C" void kernel_launch(void* const* d_in, const int* in_sizes, int n_in,
                              void* d_out, int out_size, void* d_ws, size_t ws_size,
                              hipStream_t stream) {
    const float* x   = (const float*)d_in[0];
    const float* Wp  = (const float*)d_in[1];
    const float* bpv = (const float*)d_in[2];
    const float* enc = (const float*)d_in[3];
    const float* dec = (const float*)d_in[4];
    float* out = (float*)d_out;
    float* ws  = (float*)d_ws;

    prep_kernel<<<1, 256, 0, stream>>>(enc, dec, ws);
    qae_main<<<BATCH / 256, 256, 0, stream>>>(x, Wp, bpv, ws, out);
}

// Round 7
// 106.072 us; speedup vs baseline: 1.1861x; 1.1861x over previous
//
#include <hip/hip_runtime.h>

#define BATCH 131072

typedef float v2f __attribute__((ext_vector_type(2)));

// ws layout (floats):
//  [0..53]     A: 6 matrices 3x3 (decoder collapsed: recon_k = (l^T A_k l)/(l^T l))
//  [64..99]    enc RX coeffs: gate g=bb*6+w -> ws[64+2g]=cos(tx/2), ws[65+2g]=sin(tx/2)
//  [128..511]  enc diag per block bb: ws[128+128*bb+2r]=Re D_r, +1=Im D_r

__device__ __forceinline__ float fast_tanh(float v) {
    float e = __expf(2.0f * v);
    return 1.0f - 2.0f / (e + 1.0f);
}

template <int CTRL>
__device__ __forceinline__ float dppf(float v) {
    return __int_as_float(__builtin_amdgcn_update_dpp(
        0, __float_as_int(v), CTRL, 0xF, 0xF, true));
}
#define DPP_XOR1 0xB1  // quad_perm [1,0,3,2]
#define DPP_XOR2 0x4E  // quad_perm [2,3,0,1]

// ---- forced VOP3P packed fp32 ----------------------------------------------
__device__ __forceinline__ v2f pk_mul(v2f a, v2f b) {
    v2f d; asm("v_pk_mul_f32 %0, %1, %2" : "=v"(d) : "v"(a), "v"(b)); return d;
}
__device__ __forceinline__ v2f pk_fma(v2f a, v2f b, v2f c) {  // a*b + c
    v2f d; asm("v_pk_fma_f32 %0, %1, %2, %3" : "=v"(d) : "v"(a), "v"(b), "v"(c)); return d;
}
__device__ __forceinline__ v2f pk_fma_n0(v2f a, v2f b, v2f c) {  // -a*b + c
    v2f d; asm("v_pk_fma_f32 %0, %1, %2, %3 neg_lo:[1,0,0] neg_hi:[1,0,0]"
               : "=v"(d) : "v"(a), "v"(b), "v"(c)); return d;
}
__device__ __forceinline__ v2f pk_fma_sw0(v2f a, v2f b, v2f c) {  // swap(a)*b + c
    v2f d; asm("v_pk_fma_f32 %0, %1, %2, %3 op_sel:[1,0,0] op_sel_hi:[0,1,1]"
               : "=v"(d) : "v"(a), "v"(b), "v"(c)); return d;
}
__device__ __forceinline__ v2f pk_fma_sw0n(v2f a, v2f b, v2f c) {  // -swap(a)*b + c
    v2f d; asm("v_pk_fma_f32 %0, %1, %2, %3 op_sel:[1,0,0] op_sel_hi:[0,1,1] neg_lo:[1,0,0] neg_hi:[1,0,0]"
               : "=v"(d) : "v"(a), "v"(b), "v"(c)); return d;
}
__device__ __forceinline__ v2f tanh2(v2f a) {
    return (v2f){fast_tanh(a.x), fast_tanh(a.y)};
}

// ---------------------------------------------------------------------------
// prep (unchanged)
// ---------------------------------------------------------------------------
__global__ __launch_bounds__(256) void prep_kernel(const float* __restrict__ enc_w,
                                                   const float* __restrict__ dec_w,
                                                   float* __restrict__ ws) {
    __shared__ float gt[18][8];
    __shared__ float Sr[64][8];
    __shared__ float Si[64][8];
    const int t = threadIdx.x;

    if (t < 18) {
        float tx = dec_w[t * 3 + 0];
        float tz = dec_w[t * 3 + 1];
        float c = cosf(0.5f * tx), s = sinf(0.5f * tx);
        float ch = cosf(0.5f * tz), sh = sinf(0.5f * tz);
        gt[t][0] = c * ch;  gt[t][1] = -c * sh;
        gt[t][2] = -s * sh; gt[t][3] = -s * ch;
        gt[t][4] = s * sh;  gt[t][5] = -s * ch;
        gt[t][6] = c * ch;  gt[t][7] = c * sh;
    }

    const int cl = t & 7;
    const int pr = t >> 3;
    float* fSr = &Sr[0][0];
    float* fSi = &Si[0][0];
    for (int f = t; f < 512; f += 256) {
        int r = f >> 3, c = f & 7;
        fSr[f] = (r == c && c < 3) ? 1.0f : 0.0f;
        fSi[f] = 0.0f;
    }

    for (int bb = 0; bb < 3; ++bb) {
        for (int w = 0; w < 6; ++w) {
            __syncthreads();
            int g = bb * 6 + w;
            int p = 5 - w;
            float u00r = gt[g][0], u00i = gt[g][1], u01r = gt[g][2], u01i = gt[g][3];
            float u10r = gt[g][4], u10i = gt[g][5], u11r = gt[g][6], u11i = gt[g][7];
            int r0 = ((pr >> p) << (p + 1)) | (pr & ((1 << p) - 1));
            int r1 = r0 | (1 << p);
            float ar = Sr[r0][cl], ai = Si[r0][cl];
            float br = Sr[r1][cl], bi = Si[r1][cl];
            Sr[r0][cl] = u00r * ar - u00i * ai + u01r * br - u01i * bi;
            Si[r0][cl] = u00r * ai + u00i * ar + u01r * bi + u01i * br;
            Sr[r1][cl] = u10r * ar - u10i * ai + u11r * br - u11i * bi;
            Si[r1][cl] = u10r * ai + u10i * ar + u11r * bi + u11i * br;
        }
        __syncthreads();
        for (int f = t; f < 512; f += 256) {
            int r = f >> 3;
            if (__popc(r & (r >> 1)) & 1) {
                fSr[f] = -fSr[f];
                fSi[f] = -fSi[f];
            }
        }
    }
    __syncthreads();

    if (t < 54) {
        int k = t / 9, d = (t % 9) / 3, e = t % 3;
        float acc = 0.0f;
        for (int r = 0; r < 64; ++r) {
            float term = Sr[r][d] * Sr[r][e] + Si[r][d] * Si[r][e];
            acc += ((r >> (5 - k)) & 1) ? -term : term;
        }
        ws[t] = acc;
    }

    if (t < 18) {
        float tx = enc_w[t * 3 + 0];
        ws[64 + 2 * t] = cosf(0.5f * tx);
        ws[65 + 2 * t] = sinf(0.5f * tx);
    }

    if (t >= 64 && t < 256) {
        int idx = t - 64;
        int bb = idx >> 6, r = idx & 63;
        float phi = 0.0f;
        for (int k = 0; k < 6; ++k) {
            float tz = enc_w[(bb * 6 + k) * 3 + 1];
            phi += ((r >> (5 - k)) & 1) ? 0.5f * tz : -0.5f * tz;
        }
        float sgn = (__popc(r & (r >> 1)) & 1) ? -1.0f : 1.0f;
        ws[128 + bb * 128 + 2 * r] = sgn * cosf(phi);
        ws[129 + bb * 128 + 2 * r] = sgn * sinf(phi);
    }
}

// ---------------------------------------------------------------------------
// Packed butterflies. State: 8 v2f packs/thread; pack j = (amp(m=2j), amp(m=2j+1)),
// amp r = 4m + sub, sub = lane&3.
// ---------------------------------------------------------------------------
template <int MASK>
__device__ __forceinline__ void rx_pk(v2f* zr, v2f* zi, float c, float s) {
    v2f cc = {c, c}, ss = {s, s};
#pragma unroll
    for (int j = 0; j < 8; ++j) {
        if (j & MASK) continue;
        int j1 = j | MASK;
        v2f ar = zr[j], ai = zi[j], br = zr[j1], bi = zi[j1];
        zr[j]  = pk_fma(ss, bi, pk_mul(cc, ar));
        zi[j]  = pk_fma_n0(ss, br, pk_mul(cc, ai));
        zr[j1] = pk_fma(ss, ai, pk_mul(cc, br));
        zi[j1] = pk_fma_n0(ss, ar, pk_mul(cc, bi));
    }
}

template <int MASK>  // first wire of block 0: state is real (zi = 0)
__device__ __forceinline__ void rx_pk_real(v2f* zr, v2f* zi, float c, float s) {
    v2f cc = {c, c}, sn = {-s, -s};
#pragma unroll
    for (int j = 0; j < 8; ++j) {
        if (j & MASK) continue;
        int j1 = j | MASK;
        v2f ar = zr[j], br = zr[j1];
        zr[j]  = pk_mul(cc, ar);
        zi[j]  = pk_mul(sn, br);
        zr[j1] = pk_mul(cc, br);
        zi[j1] = pk_mul(sn, ar);
    }
}

__device__ __forceinline__ void rx_inpack(v2f* zr, v2f* zi, float c, float s) {
    v2f cc = {c, c}, ss = {s, s};
#pragma unroll
    for (int j = 0; j < 8; ++j) {
        v2f orr = zr[j], oi = zi[j];
        zr[j] = pk_fma_sw0(oi, ss, pk_mul(cc, orr));
        zi[j] = pk_fma_sw0n(orr, ss, pk_mul(cc, oi));
    }
}

template <int CTRL>
__device__ __forceinline__ void rx_dpp(v2f* zr, v2f* zi, float c, float s) {
    v2f cc = {c, c}, ss = {s, s};
#pragma unroll
    for (int j = 0; j < 8; ++j) {
        v2f pr, pi;
        pr.x = dppf<CTRL>(zr[j].x);
        pr.y = dppf<CTRL>(zr[j].y);
        pi.x = dppf<CTRL>(zi[j].x);
        pi.y = dppf<CTRL>(zi[j].y);
        v2f mr = zr[j], mi = zi[j];
        zr[j] = pk_fma(ss, pi, pk_mul(cc, mr));
        zi[j] = pk_fma_n0(ss, pr, pk_mul(cc, mi));
    }
}

// one encoder block; rxc indices compile-time after inline
template <int BB>
__device__ __forceinline__ void enc_block(v2f* zr, v2f* zi, const float* rxc,
                                          const float* sD, int sub) {
    if (BB == 0) rx_pk_real<4>(zr, zi, rxc[12 * BB + 0], rxc[12 * BB + 1]);
    else         rx_pk<4>(zr, zi, rxc[12 * BB + 0], rxc[12 * BB + 1]);
    rx_pk<2>(zr, zi, rxc[12 * BB + 2], rxc[12 * BB + 3]);
    rx_pk<1>(zr, zi, rxc[12 * BB + 4], rxc[12 * BB + 5]);
    rx_inpack(zr, zi, rxc[12 * BB + 6], rxc[12 * BB + 7]);
    rx_dpp<DPP_XOR2>(zr, zi, rxc[12 * BB + 8], rxc[12 * BB + 9]);    // wire 4: lane bit1
    rx_dpp<DPP_XOR1>(zr, zi, rxc[12 * BB + 10], rxc[12 * BB + 11]);  // wire 5: lane bit0
    if (BB < 2) {
#pragma unroll
        for (int j = 0; j < 8; ++j) {
            float4 d = *(const float4*)&sD[((BB * 8 + j) * 4 + sub) * 4];
            v2f dr = {d.x, d.y}, di = {d.z, d.w};
            v2f orr = zr[j], oi = zi[j];
            zr[j] = pk_fma_n0(di, oi, pk_mul(dr, orr));
            zi[j] = pk_fma(di, orr, pk_mul(dr, oi));
        }
    }
}

// ---------------------------------------------------------------------------
// main: 4 threads/batch element; 8 v2f packs per thread (R4 structure).
// sW layout: group g = j*4+su -> phys base g*16 + (g>>2)*4.
// ---------------------------------------------------------------------------
__global__ __launch_bounds__(256) void qae_main(const float* __restrict__ x,
                                                const float* __restrict__ Wp,
                                                const float* __restrict__ bp,
                                                const float* __restrict__ ws,
                                                float* __restrict__ out) {
    __shared__ float sW[540];
    __shared__ float sD[256];
    __shared__ float sLat[192];

    const int t = threadIdx.x;
    const int bl = t >> 2;
    const int sub = t & 3;

    for (int f = t; f < 512; f += 256) {
        int g = f >> 4, e = f & 15;
        int j = g >> 2, su = g & 3;
        float val;
        if (e < 12)      { int row = 8 * j + su + 4 * (e & 1); val = Wp[row * 6 + (e >> 1)]; }
        else if (e < 14) { int row = 8 * j + su + 4 * (e - 12); val = bp[row]; }
        else val = 0.0f;
        sW[g * 16 + j * 4 + e] = val;
    }
    if (t < 128) {
        int bb = t >> 6, r = t & 63;
        int su = r & 3, m = r >> 2, j = m >> 1, hm = m & 1;
        int base = ((bb * 8 + j) * 4 + su) * 4;
        sD[base + hm]     = ws[128 + bb * 128 + 2 * r];
        sD[base + 2 + hm] = ws[128 + bb * 128 + 2 * r + 1];
    }

    // preload all gate coeffs (uniform -> s_load), while LDS fills
    float rxc[36];
#pragma unroll
    for (int i = 0; i < 36; ++i) rxc[i] = ws[64 + i];
    __syncthreads();

    const size_t b = (size_t)blockIdx.x * 64 + bl;
    const float* xp = x + b * 6;
    float2 x01 = *(const float2*)(xp);
    float2 x23 = *(const float2*)(xp + 2);
    float2 x45 = *(const float2*)(xp + 4);
    v2f xq[6];
    xq[0] = (v2f){x01.x, x01.x}; xq[1] = (v2f){x01.y, x01.y};
    xq[2] = (v2f){x23.x, x23.x}; xq[3] = (v2f){x23.y, x23.y};
    xq[4] = (v2f){x45.x, x45.x}; xq[5] = (v2f){x45.y, x45.y};

    // h = tanh(xW^T+b): pack j holds rows (8j+sub, 8j+4+sub)
    v2f zr[8], zi[8];
    v2f S2 = {0.0f, 0.0f};
#pragma unroll
    for (int j = 0; j < 8; ++j) {
        const float* wb = &sW[(j * 4 + sub) * 16 + j * 4];
        float4 c0 = *(const float4*)wb;
        float4 c1 = *(const float4*)(wb + 4);
        float4 c2 = *(const float4*)(wb + 8);
        float4 c3 = *(const float4*)(wb + 12);
        v2f a = {c3.x, c3.y};
        a = pk_fma(xq[0], (v2f){c0.x, c0.y}, a);
        a = pk_fma(xq[1], (v2f){c0.z, c0.w}, a);
        a = pk_fma(xq[2], (v2f){c1.x, c1.y}, a);
        a = pk_fma(xq[3], (v2f){c1.z, c1.w}, a);
        a = pk_fma(xq[4], (v2f){c2.x, c2.y}, a);
        a = pk_fma(xq[5], (v2f){c2.z, c2.w}, a);
        v2f th = tanh2(a);
        zr[j] = th;
        zi[j] = (v2f){0.0f, 0.0f};
        S2 = pk_fma(th, th, S2);
    }
    float S = S2.x + S2.y;
    S += dppf<DPP_XOR1>(S);
    S += dppf<DPP_XOR2>(S);
    float invS = __builtin_amdgcn_rcpf(S);

    // encoder circuit, fully unrolled (last block's diagonal dropped: |D|=1)
    enc_block<0>(zr, zi, rxc, sD, sub);
    enc_block<1>(zr, zi, rxc, sD, sub);
    enc_block<2>(zr, zi, rxc, sD, sub);

    // latent: signs from r bits 5,4,3 = j bits 2,1,0
    v2f L0 = {0, 0}, L1 = {0, 0}, L2 = {0, 0};
#pragma unroll
    for (int j = 0; j < 8; ++j) {
        v2f p = pk_fma(zi[j], zi[j], pk_mul(zr[j], zr[j]));
        L0 += (j & 4) ? -p : p;
        L1 += (j & 2) ? -p : p;
        L2 += (j & 1) ? -p : p;
    }
    float l0 = L0.x + L0.y, l1 = L1.x + L1.y, l2 = L2.x + L2.y;
    l0 += dppf<DPP_XOR1>(l0); l0 += dppf<DPP_XOR2>(l0);
    l1 += dppf<DPP_XOR1>(l1); l1 += dppf<DPP_XOR2>(l1);
    l2 += dppf<DPP_XOR1>(l2); l2 += dppf<DPP_XOR2>(l2);
    l0 *= invS; l1 *= invS; l2 *= invS;

    // decoder collapsed: recon_k = (l^T A_k l)/(l^T l)  (A uniform -> s_load)
    float r2 = l0 * l0 + l1 * l1 + l2 * l2;
    float invr2 = __builtin_amdgcn_rcpf(r2);
    float lv[3] = {l0, l1, l2};
    float rec[6];
#pragma unroll
    for (int k = 0; k < 6; ++k) {
        float acc = 0.0f;
#pragma unroll
        for (int d = 0; d < 3; ++d)
#pragma unroll
            for (int e2 = 0; e2 < 3; ++e2) acc += ws[k * 9 + d * 3 + e2] * lv[d] * lv[e2];
        rec[k] = acc * invr2;
    }

    // latent out
    if (sub == 0) {
        sLat[bl * 3 + 0] = l0;
        sLat[bl * 3 + 1] = l1;
        sLat[bl * 3 + 2] = l2;
    }
    __syncthreads();
    if (t < 192) out[(size_t)BATCH * 64 + (size_t)blockIdx.x * 192 + t] = sLat[t];

    // reconstructed = tanh(rec W^T + b); thread covers rows 16*sub..16*sub+15
    v2f rq[6];
#pragma unroll
    for (int d = 0; d < 6; ++d) rq[d] = (v2f){rec[d], rec[d]};
    const size_t ob = b * 64;
#pragma unroll
    for (int jj = 0; jj < 2; ++jj) {
        int jrow = 2 * sub + jj;
        float vlo[4], vhi[4];
#pragma unroll
        for (int su2 = 0; su2 < 4; ++su2) {
            int g = jrow * 4 + su2;
            const float* wb = &sW[g * 16 + jrow * 4];
            float4 c0 = *(const float4*)wb;
            float4 c1 = *(const float4*)(wb + 4);
            float4 c2 = *(const float4*)(wb + 8);
            float2 b2 = *(const float2*)(wb + 12);
            v2f a = {b2.x, b2.y};
            a = pk_fma(rq[0], (v2f){c0.x, c0.y}, a);
            a = pk_fma(rq[1], (v2f){c0.z, c0.w}, a);
            a = pk_fma(rq[2], (v2f){c1.x, c1.y}, a);
            a = pk_fma(rq[3], (v2f){c1.z, c1.w}, a);
            a = pk_fma(rq[4], (v2f){c2.x, c2.y}, a);
            a = pk_fma(rq[5], (v2f){c2.z, c2.w}, a);
            vlo[su2] = fast_tanh(a.x);
            vhi[su2] = fast_tanh(a.y);
        }
        float4 o0 = {vlo[0], vlo[1], vlo[2], vlo[3]};
        float4 o1 = {vhi[0], vhi[1], vhi[2], vhi[3]};
        *(float4*)&out[ob + 8 * jrow]     = o0;
        *(float4*)&out[ob + 8 * jrow + 4] = o1;
    }
}

extern "C" void kernel_launch(void* const* d_in, const int* in_sizes, int n_in,
                              void* d_out, int out_size, void* d_ws, size_t ws_size,
                              hipStream_t stream) {
    const float* x   = (const float*)d_in[0];
    const float* Wp  = (const float*)d_in[1];
    const float* bpv = (const float*)d_in[2];
    const float* enc = (const float*)d_in[3];
    const float* dec = (const float*)d_in[4];
    float* out = (float*)d_out;
    float* ws  = (float*)d_ws;

    prep_kernel<<<1, 256, 0, stream>>>(enc, dec, ws);
    qae_main<<<(BATCH * 4) / 256, 256, 0, stream>>>(x, Wp, bpv, ws, out);
}